// Round 1
// baseline (876.912 us; speedup 1.0000x reference)
//
#include <hip/hip_runtime.h>
#include <hip/hip_bf16.h>
#include <math.h>

#define NN 50000
#define EE 800000
#define GG 256

typedef short bf16x8 __attribute__((ext_vector_type(8)));
typedef float f32x4 __attribute__((ext_vector_type(4)));

__device__ __forceinline__ unsigned short f2bf(float x) {
    __hip_bfloat16 h = __float2bfloat16(x);
    union { __hip_bfloat16 h; unsigned short u; } c; c.h = h; return c.u;
}
__device__ __forceinline__ float bf2f(unsigned short u) {
    union { unsigned int v; float f; } t; t.v = ((unsigned int)u) << 16; return t.f;
}
__device__ __forceinline__ float gelu_f(float v) {
    return 0.5f * v * (1.0f + erff(v * 0.70710678118654752f));
}
// XOR swizzle for [rows][128 bf16] LDS tiles (256B row stride): spreads the
// 16-lane same-column ds_read_b128 across banks (guide G4 / T2).
__device__ __forceinline__ int swz(int row, int bytecol) {
    return row * 256 + (bytecol ^ ((row & 7) << 4));
}

// ---------------- graph prep ----------------
__global__ void k_deg(const int* __restrict__ dst, int* __restrict__ degi, int E) {
    int i = blockIdx.x * blockDim.x + threadIdx.x;
    if (i < E) atomicAdd(&degi[dst[i]], 1);
}
__global__ void k_dis(const int* __restrict__ degi, float* __restrict__ dis, int N) {
    int i = blockIdx.x * blockDim.x + threadIdx.x;
    if (i < N) dis[i] = rsqrtf((float)(degi[i] + 1)); // +1 self loop
}
__global__ void k_scan1(const int* __restrict__ degi, int* __restrict__ incl,
                        int* __restrict__ bsum, int N) {
    __shared__ int sm[1024];
    int t = threadIdx.x, i = blockIdx.x * 1024 + t;
    int v = (i < N) ? degi[i] : 0;
    sm[t] = v;
    __syncthreads();
    for (int off = 1; off < 1024; off <<= 1) {
        int add = (t >= off) ? sm[t - off] : 0;
        __syncthreads();
        sm[t] += add;
        __syncthreads();
    }
    if (i < N) incl[i] = sm[t];
    if (t == 1023) bsum[blockIdx.x] = sm[t];
}
__global__ void k_scan2(const int* __restrict__ bsum, int* __restrict__ boff, int nb) {
    if (threadIdx.x == 0 && blockIdx.x == 0) {
        int run = 0;
        for (int b = 0; b < nb; ++b) { boff[b] = run; run += bsum[b]; }
    }
}
__global__ void k_scan3(const int* __restrict__ incl, const int* __restrict__ degi,
                        const int* __restrict__ boff, int* __restrict__ rowstart, int N, int E) {
    int i = blockIdx.x * blockDim.x + threadIdx.x;
    if (i < N) rowstart[i] = incl[i] - degi[i] + boff[i >> 10];
    if (i == 0) rowstart[N] = E;
}
__global__ void k_fill(const int* __restrict__ src, const int* __restrict__ dst,
                       const float* __restrict__ dis, const int* __restrict__ rowstart,
                       int* __restrict__ fillc, int* __restrict__ col,
                       float* __restrict__ wn, int E) {
    int i = blockIdx.x * blockDim.x + threadIdx.x;
    if (i < E) {
        int s = src[i], d = dst[i];
        int pos = rowstart[d] + atomicAdd(&fillc[d], 1);
        col[pos] = s;
        wn[pos] = dis[s] * dis[d];
    }
}
// W[k][n] fp32 -> Wt bf16, layout row=n (transposed), pre-swizzled for linear LDS copy
__global__ void k_prepw(const float* __restrict__ W, unsigned short* __restrict__ Wt) {
    int tid = blockIdx.x * blockDim.x + threadIdx.x; // 16384
    int n = tid >> 7, k = tid & 127;
    float v = W[k * 128 + n];
    *(unsigned short*)((char*)Wt + swz(n, k * 2)) = f2bf(v);
}
__global__ void k_gbounds(const int* __restrict__ batch, int* __restrict__ gstart, int N, int G) {
    int g = blockIdx.x * blockDim.x + threadIdx.x;
    if (g > G) return;
    int lo = 0, hi = N;
    while (lo < hi) { int mid = (lo + hi) >> 1; if (batch[mid] < g) lo = mid + 1; else hi = mid; }
    gstart[g] = lo;
}

// ---------------- fused GEMM: out = epi(A' @ W + b) ----------------
// A' = A (fp32 or bf16), optional per-channel affine (BN) on load.
// epi: optional GELU, optional residual (+BN affine on residual), fp32/bf16 outs.
__global__ __launch_bounds__(256) void k_gemm(
    const float* __restrict__ A32, const unsigned short* __restrict__ A16,
    const unsigned short* __restrict__ Wt, const float* __restrict__ bias,
    const float* __restrict__ lscale, const float* __restrict__ lshift,
    int gelu,
    const float* __restrict__ res32, const float* __restrict__ rscale, const float* __restrict__ rshift,
    float* __restrict__ out32, unsigned short* __restrict__ out16, int M)
{
    __shared__ unsigned short As[64 * 128];
    __shared__ unsigned short Ws[128 * 128];
    const int tid = threadIdx.x;
    const int bm = blockIdx.x * 64;
    { // pre-swizzled weights -> LDS, linear 16B copy
        const uint4* srcp = (const uint4*)Wt;
        uint4* dstp = (uint4*)Ws;
        for (int i = tid; i < (128 * 128) / 8; i += 256) dstp[i] = srcp[i];
    }
    // A tile (64 rows x 128) -> LDS bf16, swizzled; 4 passes of 16 rows
    #pragma unroll
    for (int pass = 0; pass < 4; ++pass) {
        int row = pass * 16 + (tid >> 4);
        int c8 = tid & 15;
        int gr = bm + row; if (gr > M - 1) gr = M - 1;
        unsigned short tmp[8];
        if (A32) {
            const float* pp = A32 + (size_t)gr * 128 + c8 * 8;
            float4 v0 = *(const float4*)pp;
            float4 v1 = *(const float4*)(pp + 4);
            float vv[8] = { v0.x, v0.y, v0.z, v0.w, v1.x, v1.y, v1.z, v1.w };
            if (lscale) {
                int ch = c8 * 8;
                #pragma unroll
                for (int j = 0; j < 8; ++j) vv[j] = vv[j] * lscale[ch + j] + lshift[ch + j];
            }
            #pragma unroll
            for (int j = 0; j < 8; ++j) tmp[j] = f2bf(vv[j]);
        } else {
            *(uint4*)tmp = *(const uint4*)(A16 + (size_t)gr * 128 + c8 * 8);
        }
        *(uint4*)((char*)As + swz(row, c8 * 16)) = *(uint4*)tmp;
    }
    __syncthreads();

    const int lane = tid & 63, wid = tid >> 6;
    const int r0 = wid * 16;           // wave's 16-row slab
    const int lrow = lane & 15;
    const int lkb = (lane >> 4) * 16;  // byte offset of this lane's 8-elem k chunk
    f32x4 acc[8];
    #pragma unroll
    for (int n = 0; n < 8; ++n) acc[n] = (f32x4){0.f, 0.f, 0.f, 0.f};
    #pragma unroll
    for (int kk = 0; kk < 4; ++kk) {
        int bc = kk * 64 + lkb;
        bf16x8 a = *(const bf16x8*)((const char*)As + swz(r0 + lrow, bc));
        #pragma unroll
        for (int n = 0; n < 8; ++n) {
            bf16x8 b = *(const bf16x8*)((const char*)Ws + swz(n * 16 + lrow, bc));
            acc[n] = __builtin_amdgcn_mfma_f32_16x16x32_bf16(a, b, acc[n], 0, 0, 0);
        }
    }
    // epilogue: C/D map col=lane&15, row=(lane>>4)*4+j (m89-verified)
    const int cb = lane & 15;
    const int rb = r0 + (lane >> 4) * 4;
    #pragma unroll
    for (int n = 0; n < 8; ++n) {
        int colg = n * 16 + cb;
        float bv = bias ? bias[colg] : 0.f;
        #pragma unroll
        for (int j = 0; j < 4; ++j) {
            int rowg = bm + rb + j;
            if (rowg < M) {
                float v = acc[n][j] + bv;
                if (gelu) v = gelu_f(v);
                if (res32) {
                    float r = res32[(size_t)rowg * 128 + colg];
                    if (rscale) r = r * rscale[colg] + rshift[colg];
                    v += r;
                }
                if (out32) out32[(size_t)rowg * 128 + colg] = v;
                if (out16) out16[(size_t)rowg * 128 + colg] = f2bf(v);
            }
        }
    }
}

// ---------------- CSR aggregation + residual + BN partial stats ----------------
// z[v] = sum_{u->v} norm * xw[u] + (1/deg)*xw[v] + conv_b + x0[v]; accumulate sum/sumsq.
__global__ __launch_bounds__(256) void k_agg(
    const unsigned short* __restrict__ xw, const int* __restrict__ rowstart,
    const int* __restrict__ col, const float* __restrict__ wn,
    const float* __restrict__ dis, const float* __restrict__ convb,
    const float* __restrict__ x0, float* __restrict__ z,
    float* __restrict__ bnsum, float* __restrict__ bnsq, int N)
{
    const int lane = threadIdx.x & 63;
    const int wave = blockIdx.x * 4 + (threadIdx.x >> 6);
    const int nwaves = gridDim.x * 4;
    const int ch = lane * 2; // each lane owns 2 channels
    const float cb0 = convb[ch], cb1 = convb[ch + 1];
    float s0 = 0, s1 = 0, q0 = 0, q1 = 0;
    for (int v = wave; v < N; v += nwaves) {
        float a0 = 0, a1 = 0;
        const int e0 = rowstart[v], e1 = rowstart[v + 1];
        for (int e = e0; e < e1; ++e) {
            int u = col[e];
            float w = wn[e];
            unsigned int p = *(const unsigned int*)(xw + (size_t)u * 128 + ch);
            a0 += w * bf2f((unsigned short)(p & 0xffff));
            a1 += w * bf2f((unsigned short)(p >> 16));
        }
        float dv = dis[v];
        float sw = dv * dv; // self-loop norm
        unsigned int p = *(const unsigned int*)(xw + (size_t)v * 128 + ch);
        a0 += sw * bf2f((unsigned short)(p & 0xffff));
        a1 += sw * bf2f((unsigned short)(p >> 16));
        float2 xr = *(const float2*)(x0 + (size_t)v * 128 + ch);
        float z0 = a0 + cb0 + xr.x;
        float z1 = a1 + cb1 + xr.y;
        *(float2*)(z + (size_t)v * 128 + ch) = make_float2(z0, z1);
        s0 += z0; q0 += z0 * z0; s1 += z1; q1 += z1 * z1;
    }
    __shared__ float red[1024];
    const int t = threadIdx.x;
    red[t] = s0; red[256 + t] = s1; red[512 + t] = q0; red[768 + t] = q1;
    __syncthreads();
    if (t < 64) {
        float r0 = red[t] + red[t + 64] + red[t + 128] + red[t + 192];
        float r1 = red[256 + t] + red[256 + t + 64] + red[256 + t + 128] + red[256 + t + 192];
        float r2 = red[512 + t] + red[512 + t + 64] + red[512 + t + 128] + red[512 + t + 192];
        float r3 = red[768 + t] + red[768 + t + 64] + red[768 + t + 128] + red[768 + t + 192];
        int c = t * 2;
        atomicAdd(&bnsum[c], r0);
        atomicAdd(&bnsum[c + 1], r1);
        atomicAdd(&bnsq[c], r2);
        atomicAdd(&bnsq[c + 1], r3);
    }
}
__global__ void k_bnfin(const float* __restrict__ bnsum, const float* __restrict__ bnsq,
                        const float* __restrict__ gamma, const float* __restrict__ beta,
                        float* __restrict__ scale, float* __restrict__ shift, float invN) {
    int c = threadIdx.x;
    float m = bnsum[c] * invN;
    float var = bnsq[c] * invN - m * m;
    float s = gamma[c] * rsqrtf(var + 1e-5f);
    scale[c] = s;
    shift[c] = beta[c] - m * s;
}
__global__ __launch_bounds__(128) void k_pool(const float* __restrict__ x,
                                              const int* __restrict__ gstart,
                                              float* __restrict__ pooled, int G) {
    int g = blockIdx.x, t = threadIdx.x;
    int s = gstart[g], e = gstart[g + 1];
    float acc = 0;
    for (int v = s; v < e; ++v) acc += x[(size_t)v * 128 + t];
    pooled[g * 128 + t] = acc / fmaxf((float)(e - s), 1.0f);
}
// post FFNN in exact fp32 (tiny): out[g] = gelu(pooled@w1+b1)@w2+b2
__global__ __launch_bounds__(128) void k_post(const float* __restrict__ pooled,
                                              const float* __restrict__ w1, const float* __restrict__ b1,
                                              const float* __restrict__ w2, const float* __restrict__ b2,
                                              float* __restrict__ out, int G) {
    __shared__ float pr[128], hr[128];
    int g = blockIdx.x, t = threadIdx.x;
    pr[t] = pooled[g * 128 + t];
    __syncthreads();
    float a = b1[t];
    for (int k = 0; k < 128; ++k) a += pr[k] * w1[k * 128 + t];
    hr[t] = gelu_f(a);
    __syncthreads();
    if (t < 64) {
        float o = b2[t];
        for (int k = 0; k < 128; ++k) o += hr[k] * w2[k * 64 + t];
        out[g * 64 + t] = o;
    }
}

extern "C" void kernel_launch(void* const* d_in, const int* in_sizes, int n_in,
                              void* d_out, int out_size, void* d_ws, size_t ws_size,
                              hipStream_t stream) {
    (void)in_sizes; (void)n_in; (void)out_size; (void)ws_size;
    const float* x_in    = (const float*)d_in[0];
    const int*   ei      = (const int*)d_in[1];
    const int*   batch   = (const int*)d_in[2];
    const float* pre_w1  = (const float*)d_in[3];
    const float* pre_b1  = (const float*)d_in[4];
    const float* pre_w2  = (const float*)d_in[5];
    const float* pre_b2  = (const float*)d_in[6];
    const float* conv_w  = (const float*)d_in[7];
    const float* conv_b  = (const float*)d_in[8];
    const float* ffnn_w1 = (const float*)d_in[9];
    const float* ffnn_b1 = (const float*)d_in[10];
    const float* ffnn_w2 = (const float*)d_in[11];
    const float* ffnn_b2 = (const float*)d_in[12];
    const float* bn_gamma= (const float*)d_in[13];
    const float* bn_beta = (const float*)d_in[14];
    const float* post_w1 = (const float*)d_in[15];
    const float* post_b1 = (const float*)d_in[16];
    const float* post_w2 = (const float*)d_in[17];
    const float* post_b2 = (const float*)d_in[18];
    const int* srcE = ei;
    const int* dstE = ei + EE;

    char* base = (char*)d_ws;
    size_t off = 0;
    auto carve = [&](size_t bytes) {
        char* q = base + off;
        off = (off + bytes + 255) & ~(size_t)255;
        return q;
    };
    float* xf32 = (float*)carve((size_t)NN * 128 * 4);           // current features fp32
    float* zf32 = (float*)carve((size_t)NN * 128 * 4);           // pre-BN hop features
    unsigned short* xbf = (unsigned short*)carve((size_t)NN * 128 * 2); // bf16 mirror of x
    unsigned short* hbf = (unsigned short*)carve((size_t)NN * 128 * 2); // scratch bf16 (h / xw)
    float* dis   = (float*)carve((size_t)NN * 4);
    int* degi    = (int*)carve((size_t)NN * 4);
    int* fillc   = (int*)carve((size_t)NN * 4);
    int* incl    = (int*)carve((size_t)NN * 4);
    int* bsum    = (int*)carve(64 * 4);
    int* boff    = (int*)carve(64 * 4);
    int* rowstart= (int*)carve((size_t)(NN + 1) * 4);
    int* colx    = (int*)carve((size_t)EE * 4);
    float* wn    = (float*)carve((size_t)EE * 4);
    unsigned short* Wt[8];
    for (int i = 0; i < 8; ++i) Wt[i] = (unsigned short*)carve(128 * 128 * 2);
    float* bnsumb  = (float*)carve(128 * 4);
    float* bnsqb   = (float*)carve(128 * 4);
    float* bnscale = (float*)carve(128 * 4);
    float* bnshift = (float*)carve(128 * 4);
    int* gstart    = (int*)carve((size_t)(GG + 1) * 4);
    float* pooled  = (float*)carve((size_t)GG * 128 * 4);

    hipMemsetAsync(degi, 0, (size_t)NN * 4, stream);
    hipMemsetAsync(fillc, 0, (size_t)NN * 4, stream);

    k_deg<<<(EE + 255) / 256, 256, 0, stream>>>(dstE, degi, EE);
    k_dis<<<(NN + 255) / 256, 256, 0, stream>>>(degi, dis, NN);
    const int nsb = (NN + 1023) / 1024;
    k_scan1<<<nsb, 1024, 0, stream>>>(degi, incl, bsum, NN);
    k_scan2<<<1, 1, 0, stream>>>(bsum, boff, nsb);
    k_scan3<<<(NN + 255) / 256, 256, 0, stream>>>(incl, degi, boff, rowstart, NN, EE);
    k_fill<<<(EE + 255) / 256, 256, 0, stream>>>(srcE, dstE, dis, rowstart, fillc, colx, wn, EE);

    const float* wsrc[8] = { pre_w1, pre_w2, conv_w, conv_w + 16384,
                             ffnn_w1, ffnn_w1 + 16384, ffnn_w2, ffnn_w2 + 16384 };
    for (int i = 0; i < 8; ++i) k_prepw<<<64, 256, 0, stream>>>(wsrc[i], Wt[i]);
    k_gbounds<<<2, 256, 0, stream>>>(batch, gstart, NN, GG);

    const int gB = (NN + 63) / 64;
    // preprocess FFNN: h = gelu(x@w1+b1) [bf16]; x = h@w2+b2 [fp32+bf16]
    k_gemm<<<gB, 256, 0, stream>>>(x_in, nullptr, Wt[0], pre_b1, nullptr, nullptr, 1,
                                   nullptr, nullptr, nullptr, nullptr, hbf, NN);
    k_gemm<<<gB, 256, 0, stream>>>(nullptr, hbf, Wt[1], pre_b2, nullptr, nullptr, 0,
                                   nullptr, nullptr, nullptr, xf32, xbf, NN);
    for (int i = 0; i < 2; ++i) {
        // xw = x@conv_w [bf16, into hbf scratch]
        k_gemm<<<gB, 256, 0, stream>>>(nullptr, xbf, Wt[2 + i], nullptr, nullptr, nullptr, 0,
                                       nullptr, nullptr, nullptr, nullptr, hbf, NN);
        hipMemsetAsync(bnsumb, 0, 128 * 4, stream);
        hipMemsetAsync(bnsqb, 0, 128 * 4, stream);
        // z = agg(xw) + conv_b + x ; BN partial stats
        k_agg<<<512, 256, 0, stream>>>(hbf, rowstart, colx, wn, dis, conv_b + i * 128,
                                       xf32, zf32, bnsumb, bnsqb, NN);
        k_bnfin<<<1, 128, 0, stream>>>(bnsumb, bnsqb, bn_gamma + i * 128, bn_beta + i * 128,
                                       bnscale, bnshift, 1.0f / NN);
        // h = gelu(BN(z)@w1+b1) [bf16]
        k_gemm<<<gB, 256, 0, stream>>>(zf32, nullptr, Wt[4 + i], ffnn_b1 + i * 128, bnscale, bnshift, 1,
                                       nullptr, nullptr, nullptr, nullptr, hbf, NN);
        // x = h@w2+b2 + BN(z) [fp32+bf16]
        k_gemm<<<gB, 256, 0, stream>>>(nullptr, hbf, Wt[6 + i], ffnn_b2 + i * 128, nullptr, nullptr, 0,
                                       zf32, bnscale, bnshift, xf32, xbf, NN);
    }
    k_pool<<<GG, 128, 0, stream>>>(xf32, gstart, pooled, GG);
    k_post<<<GG, 128, 0, stream>>>(pooled, post_w1, post_b1, post_w2, post_b2, (float*)d_out, GG);
}

// Round 2
// 587.402 us; speedup vs baseline: 1.4929x; 1.4929x over previous
//
#include <hip/hip_runtime.h>
#include <hip/hip_bf16.h>
#include <math.h>

#define NN 50000
#define EE 800000
#define GG 256

typedef short bf16x8 __attribute__((ext_vector_type(8)));
typedef float f32x4 __attribute__((ext_vector_type(4)));

__device__ __forceinline__ unsigned short f2bf(float x) {
    __hip_bfloat16 h = __float2bfloat16(x);
    union { __hip_bfloat16 h; unsigned short u; } c; c.h = h; return c.u;
}
__device__ __forceinline__ float bf2f(unsigned short u) {
    union { unsigned int v; float f; } t; t.v = ((unsigned int)u) << 16; return t.f;
}
__device__ __forceinline__ float gelu_f(float v) {
    return 0.5f * v * (1.0f + erff(v * 0.70710678118654752f));
}
// XOR swizzle for [rows][128 bf16] LDS tiles (256B row stride): spreads the
// 16-lane same-column ds_read_b128 across banks (guide G4 / T2).
__device__ __forceinline__ int swz(int row, int bytecol) {
    return row * 256 + (bytecol ^ ((row & 7) << 4));
}

// ---------------- graph prep ----------------
__global__ void k_deg(const int* __restrict__ dst, int* __restrict__ degi, int E) {
    int i = blockIdx.x * blockDim.x + threadIdx.x;
    if (i < E) atomicAdd(&degi[dst[i]], 1);
}
__global__ void k_dis(const int* __restrict__ degi, float* __restrict__ dis, int N) {
    int i = blockIdx.x * blockDim.x + threadIdx.x;
    if (i < N) dis[i] = rsqrtf((float)(degi[i] + 1)); // +1 self loop
}
__global__ void k_scan1(const int* __restrict__ degi, int* __restrict__ incl,
                        int* __restrict__ bsum, int N) {
    __shared__ int sm[1024];
    int t = threadIdx.x, i = blockIdx.x * 1024 + t;
    int v = (i < N) ? degi[i] : 0;
    sm[t] = v;
    __syncthreads();
    for (int off = 1; off < 1024; off <<= 1) {
        int add = (t >= off) ? sm[t - off] : 0;
        __syncthreads();
        sm[t] += add;
        __syncthreads();
    }
    if (i < N) incl[i] = sm[t];
    if (t == 1023) bsum[blockIdx.x] = sm[t];
}
__global__ void k_scan2(const int* __restrict__ bsum, int* __restrict__ boff, int nb) {
    if (threadIdx.x == 0 && blockIdx.x == 0) {
        int run = 0;
        for (int b = 0; b < nb; ++b) { boff[b] = run; run += bsum[b]; }
    }
}
__global__ void k_scan3(const int* __restrict__ incl, const int* __restrict__ degi,
                        const int* __restrict__ boff, int* __restrict__ rowstart, int N, int E) {
    int i = blockIdx.x * blockDim.x + threadIdx.x;
    if (i < N) rowstart[i] = incl[i] - degi[i] + boff[i >> 10];
    if (i == 0) rowstart[N] = E;
}
__global__ void k_fill(const int* __restrict__ src, const int* __restrict__ dst,
                       const float* __restrict__ dis, const int* __restrict__ rowstart,
                       int* __restrict__ fillc, int* __restrict__ col,
                       float* __restrict__ wn, int E) {
    int i = blockIdx.x * blockDim.x + threadIdx.x;
    if (i < E) {
        int s = src[i], d = dst[i];
        int pos = rowstart[d] + atomicAdd(&fillc[d], 1);
        col[pos] = s;
        wn[pos] = dis[s] * dis[d];
    }
}
// W[k][n] fp32 -> Wt bf16, layout row=n (transposed), pre-swizzled for linear LDS copy
__global__ void k_prepw(const float* __restrict__ W, unsigned short* __restrict__ Wt) {
    int tid = blockIdx.x * blockDim.x + threadIdx.x; // 16384
    int n = tid >> 7, k = tid & 127;
    float v = W[k * 128 + n];
    *(unsigned short*)((char*)Wt + swz(n, k * 2)) = f2bf(v);
}
__global__ void k_gbounds(const int* __restrict__ batch, int* __restrict__ gstart, int N, int G) {
    int g = blockIdx.x * blockDim.x + threadIdx.x;
    if (g > G) return;
    int lo = 0, hi = N;
    while (lo < hi) { int mid = (lo + hi) >> 1; if (batch[mid] < g) lo = mid + 1; else hi = mid; }
    gstart[g] = lo;
}

// ---------------- fused GEMM: out = epi(A' @ W + b) ----------------
__global__ __launch_bounds__(256) void k_gemm(
    const float* __restrict__ A32, const unsigned short* __restrict__ A16,
    const unsigned short* __restrict__ Wt, const float* __restrict__ bias,
    const float* __restrict__ lscale, const float* __restrict__ lshift,
    int gelu,
    const float* __restrict__ res32, const float* __restrict__ rscale, const float* __restrict__ rshift,
    float* __restrict__ out32, unsigned short* __restrict__ out16, int M)
{
    __shared__ unsigned short As[64 * 128];
    __shared__ unsigned short Ws[128 * 128];
    const int tid = threadIdx.x;
    const int bm = blockIdx.x * 64;
    { // pre-swizzled weights -> LDS, linear 16B copy
        const uint4* srcp = (const uint4*)Wt;
        uint4* dstp = (uint4*)Ws;
        for (int i = tid; i < (128 * 128) / 8; i += 256) dstp[i] = srcp[i];
    }
    // A tile (64 rows x 128) -> LDS bf16, swizzled; 4 passes of 16 rows
    #pragma unroll
    for (int pass = 0; pass < 4; ++pass) {
        int row = pass * 16 + (tid >> 4);
        int c8 = tid & 15;
        int gr = bm + row; if (gr > M - 1) gr = M - 1;
        unsigned short tmp[8];
        if (A32) {
            const float* pp = A32 + (size_t)gr * 128 + c8 * 8;
            float4 v0 = *(const float4*)pp;
            float4 v1 = *(const float4*)(pp + 4);
            float vv[8] = { v0.x, v0.y, v0.z, v0.w, v1.x, v1.y, v1.z, v1.w };
            if (lscale) {
                int ch = c8 * 8;
                #pragma unroll
                for (int j = 0; j < 8; ++j) vv[j] = vv[j] * lscale[ch + j] + lshift[ch + j];
            }
            #pragma unroll
            for (int j = 0; j < 8; ++j) tmp[j] = f2bf(vv[j]);
        } else {
            *(uint4*)tmp = *(const uint4*)(A16 + (size_t)gr * 128 + c8 * 8);
        }
        *(uint4*)((char*)As + swz(row, c8 * 16)) = *(uint4*)tmp;
    }
    __syncthreads();

    const int lane = tid & 63, wid = tid >> 6;
    const int r0 = wid * 16;           // wave's 16-row slab
    const int lrow = lane & 15;
    const int lkb = (lane >> 4) * 16;  // byte offset of this lane's 8-elem k chunk
    f32x4 acc[8];
    #pragma unroll
    for (int n = 0; n < 8; ++n) acc[n] = (f32x4){0.f, 0.f, 0.f, 0.f};
    #pragma unroll
    for (int kk = 0; kk < 4; ++kk) {
        int bc = kk * 64 + lkb;
        bf16x8 a = *(const bf16x8*)((const char*)As + swz(r0 + lrow, bc));
        #pragma unroll
        for (int n = 0; n < 8; ++n) {
            bf16x8 b = *(const bf16x8*)((const char*)Ws + swz(n * 16 + lrow, bc));
            acc[n] = __builtin_amdgcn_mfma_f32_16x16x32_bf16(a, b, acc[n], 0, 0, 0);
        }
    }
    // epilogue: C/D map col=lane&15, row=(lane>>4)*4+j (m89-verified)
    const int cb = lane & 15;
    const int rb = r0 + (lane >> 4) * 4;
    #pragma unroll
    for (int n = 0; n < 8; ++n) {
        int colg = n * 16 + cb;
        float bv = bias ? bias[colg] : 0.f;
        #pragma unroll
        for (int j = 0; j < 4; ++j) {
            int rowg = bm + rb + j;
            if (rowg < M) {
                float v = acc[n][j] + bv;
                if (gelu) v = gelu_f(v);
                if (res32) {
                    float r = res32[(size_t)rowg * 128 + colg];
                    if (rscale) r = r * rscale[colg] + rshift[colg];
                    v += r;
                }
                if (out32) out32[(size_t)rowg * 128 + colg] = v;
                if (out16) out16[(size_t)rowg * 128 + colg] = f2bf(v);
            }
        }
    }
}

// ---------------- CSR aggregation + residual + BN partial stats ----------------
// Wave-per-node (grid-stride), 4 edges/iter (16 lanes x 16B each), prefetched
// col/wn, butterfly reduce across edge groups; g==0 lanes finalize + BN stats.
__global__ __launch_bounds__(256) void k_agg(
    const unsigned short* __restrict__ xw, const int* __restrict__ rowstart,
    const int* __restrict__ col, const float* __restrict__ wn,
    const float* __restrict__ dis, const float* __restrict__ convb,
    const float* __restrict__ x0, float* __restrict__ z,
    float* __restrict__ bnsum, float* __restrict__ bnsq, int N)
{
    __shared__ float redS[4][128];
    __shared__ float redQ[4][128];
    const int tid = threadIdx.x;
    const int lane = tid & 63;
    const int wid = tid >> 6;
    const int g = lane >> 4;        // edge sub-group 0..3
    const int cl = lane & 15;       // channel lane 0..15
    const int ch = cl * 8;          // owns 8 channels
    const int wave = blockIdx.x * 4 + wid;
    const int nwaves = gridDim.x * 4;

    float cb[8];
    #pragma unroll
    for (int j = 0; j < 8; ++j) cb[j] = convb[ch + j];
    float s[8], q[8];
    #pragma unroll
    for (int j = 0; j < 8; ++j) { s[j] = 0.f; q[j] = 0.f; }

    for (int v = wave; v < N; v += nwaves) {
        const int e0 = rowstart[v], e1 = rowstart[v + 1];
        float a[8];
        #pragma unroll
        for (int j = 0; j < 8; ++j) a[j] = 0.f;
        int e = e0 + g;
        bool valid = e < e1;
        int u_nx = 0; float w_nx = 0.f;
        if (valid) { u_nx = col[e]; w_nx = wn[e]; }
        while (valid) {
            const int u = u_nx;
            const float w = w_nx;
            uint4 p = *(const uint4*)(xw + (size_t)u * 128 + ch);
            e += 4;
            valid = e < e1;
            if (valid) { u_nx = col[e]; w_nx = wn[e]; }
            const unsigned int pw[4] = { p.x, p.y, p.z, p.w };
            #pragma unroll
            for (int d = 0; d < 4; ++d) {
                a[2 * d]     += w * bf2f((unsigned short)(pw[d] & 0xffff));
                a[2 * d + 1] += w * bf2f((unsigned short)(pw[d] >> 16));
            }
        }
        #pragma unroll
        for (int j = 0; j < 8; ++j) {
            a[j] += __shfl_xor(a[j], 16, 64);
            a[j] += __shfl_xor(a[j], 32, 64);
        }
        if (g == 0) {
            const float dv = dis[v];
            const float sw = dv * dv; // self-loop norm
            uint4 p = *(const uint4*)(xw + (size_t)v * 128 + ch);
            const unsigned int pw[4] = { p.x, p.y, p.z, p.w };
            float4 xa = *(const float4*)(x0 + (size_t)v * 128 + ch);
            float4 xb = *(const float4*)(x0 + (size_t)v * 128 + ch + 4);
            const float xr[8] = { xa.x, xa.y, xa.z, xa.w, xb.x, xb.y, xb.z, xb.w };
            float zz[8];
            #pragma unroll
            for (int d = 0; d < 4; ++d) {
                zz[2 * d]     = a[2 * d]     + sw * bf2f((unsigned short)(pw[d] & 0xffff));
                zz[2 * d + 1] = a[2 * d + 1] + sw * bf2f((unsigned short)(pw[d] >> 16));
            }
            #pragma unroll
            for (int j = 0; j < 8; ++j) {
                zz[j] += cb[j] + xr[j];
                s[j] += zz[j];
                q[j] += zz[j] * zz[j];
            }
            *(float4*)(z + (size_t)v * 128 + ch)     = make_float4(zz[0], zz[1], zz[2], zz[3]);
            *(float4*)(z + (size_t)v * 128 + ch + 4) = make_float4(zz[4], zz[5], zz[6], zz[7]);
        }
    }
    if (g == 0) {
        #pragma unroll
        for (int j = 0; j < 8; ++j) { redS[wid][ch + j] = s[j]; redQ[wid][ch + j] = q[j]; }
    }
    __syncthreads();
    if (tid < 128) {
        float ts = redS[0][tid] + redS[1][tid] + redS[2][tid] + redS[3][tid];
        float tq = redQ[0][tid] + redQ[1][tid] + redQ[2][tid] + redQ[3][tid];
        atomicAdd(&bnsum[tid], ts);
        atomicAdd(&bnsq[tid], tq);
    }
}
__global__ void k_bnfin(float* __restrict__ bnsum, float* __restrict__ bnsq,
                        const float* __restrict__ gamma, const float* __restrict__ beta,
                        float* __restrict__ scale, float* __restrict__ shift, float invN) {
    int c = threadIdx.x;
    float m = bnsum[c] * invN;
    float var = bnsq[c] * invN - m * m;
    float s = gamma[c] * rsqrtf(var + 1e-5f);
    scale[c] = s;
    shift[c] = beta[c] - m * s;
    bnsum[c] = 0.f;  // re-zero for next hop (memsets hoisted out of hop loop)
    bnsq[c] = 0.f;
}
__global__ __launch_bounds__(128) void k_pool(const float* __restrict__ x,
                                              const int* __restrict__ gstart,
                                              float* __restrict__ pooled, int G) {
    int g = blockIdx.x, t = threadIdx.x;
    int s = gstart[g], e = gstart[g + 1];
    float acc = 0;
    for (int v = s; v < e; ++v) acc += x[(size_t)v * 128 + t];
    pooled[g * 128 + t] = acc / fmaxf((float)(e - s), 1.0f);
}
// post FFNN in exact fp32 (tiny): out[g] = gelu(pooled@w1+b1)@w2+b2
__global__ __launch_bounds__(128) void k_post(const float* __restrict__ pooled,
                                              const float* __restrict__ w1, const float* __restrict__ b1,
                                              const float* __restrict__ w2, const float* __restrict__ b2,
                                              float* __restrict__ out, int G) {
    __shared__ float pr[128], hr[128];
    int g = blockIdx.x, t = threadIdx.x;
    pr[t] = pooled[g * 128 + t];
    __syncthreads();
    float a = b1[t];
    for (int k = 0; k < 128; ++k) a += pr[k] * w1[k * 128 + t];
    hr[t] = gelu_f(a);
    __syncthreads();
    if (t < 64) {
        float o = b2[t];
        for (int k = 0; k < 128; ++k) o += hr[k] * w2[k * 64 + t];
        out[g * 64 + t] = o;
    }
}

extern "C" void kernel_launch(void* const* d_in, const int* in_sizes, int n_in,
                              void* d_out, int out_size, void* d_ws, size_t ws_size,
                              hipStream_t stream) {
    (void)in_sizes; (void)n_in; (void)out_size; (void)ws_size;
    const float* x_in    = (const float*)d_in[0];
    const int*   ei      = (const int*)d_in[1];
    const int*   batch   = (const int*)d_in[2];
    const float* pre_w1  = (const float*)d_in[3];
    const float* pre_b1  = (const float*)d_in[4];
    const float* pre_w2  = (const float*)d_in[5];
    const float* pre_b2  = (const float*)d_in[6];
    const float* conv_w  = (const float*)d_in[7];
    const float* conv_b  = (const float*)d_in[8];
    const float* ffnn_w1 = (const float*)d_in[9];
    const float* ffnn_b1 = (const float*)d_in[10];
    const float* ffnn_w2 = (const float*)d_in[11];
    const float* ffnn_b2 = (const float*)d_in[12];
    const float* bn_gamma= (const float*)d_in[13];
    const float* bn_beta = (const float*)d_in[14];
    const float* post_w1 = (const float*)d_in[15];
    const float* post_b1 = (const float*)d_in[16];
    const float* post_w2 = (const float*)d_in[17];
    const float* post_b2 = (const float*)d_in[18];
    const int* srcE = ei;
    const int* dstE = ei + EE;

    char* base = (char*)d_ws;
    size_t off = 0;
    auto carve = [&](size_t bytes) {
        char* q = base + off;
        off = (off + bytes + 255) & ~(size_t)255;
        return q;
    };
    float* xf32 = (float*)carve((size_t)NN * 128 * 4);
    float* zf32 = (float*)carve((size_t)NN * 128 * 4);
    unsigned short* xbf = (unsigned short*)carve((size_t)NN * 128 * 2);
    unsigned short* hbf = (unsigned short*)carve((size_t)NN * 128 * 2);
    float* dis   = (float*)carve((size_t)NN * 4);
    int* degi    = (int*)carve((size_t)NN * 4);
    int* fillc   = (int*)carve((size_t)NN * 4);
    int* incl    = (int*)carve((size_t)NN * 4);
    int* bsum    = (int*)carve(64 * 4);
    int* boff    = (int*)carve(64 * 4);
    int* rowstart= (int*)carve((size_t)(NN + 1) * 4);
    int* colx    = (int*)carve((size_t)EE * 4);
    float* wn    = (float*)carve((size_t)EE * 4);
    unsigned short* Wt[8];
    for (int i = 0; i < 8; ++i) Wt[i] = (unsigned short*)carve(128 * 128 * 2);
    float* bnsumb  = (float*)carve(128 * 4);
    float* bnsqb   = (float*)carve(128 * 4);
    float* bnscale = (float*)carve(128 * 4);
    float* bnshift = (float*)carve(128 * 4);
    int* gstart    = (int*)carve((size_t)(GG + 1) * 4);
    float* pooled  = (float*)carve((size_t)GG * 128 * 4);

    hipMemsetAsync(degi, 0, (size_t)NN * 4, stream);
    hipMemsetAsync(fillc, 0, (size_t)NN * 4, stream);
    hipMemsetAsync(bnsumb, 0, 128 * 4, stream);
    hipMemsetAsync(bnsqb, 0, 128 * 4, stream);

    k_deg<<<(EE + 255) / 256, 256, 0, stream>>>(dstE, degi, EE);
    k_dis<<<(NN + 255) / 256, 256, 0, stream>>>(degi, dis, NN);
    const int nsb = (NN + 1023) / 1024;
    k_scan1<<<nsb, 1024, 0, stream>>>(degi, incl, bsum, NN);
    k_scan2<<<1, 1, 0, stream>>>(bsum, boff, nsb);
    k_scan3<<<(NN + 255) / 256, 256, 0, stream>>>(incl, degi, boff, rowstart, NN, EE);
    k_fill<<<(EE + 255) / 256, 256, 0, stream>>>(srcE, dstE, dis, rowstart, fillc, colx, wn, EE);

    const float* wsrc[8] = { pre_w1, pre_w2, conv_w, conv_w + 16384,
                             ffnn_w1, ffnn_w1 + 16384, ffnn_w2, ffnn_w2 + 16384 };
    for (int i = 0; i < 8; ++i) k_prepw<<<64, 256, 0, stream>>>(wsrc[i], Wt[i]);
    k_gbounds<<<2, 256, 0, stream>>>(batch, gstart, NN, GG);

    const int gB = (NN + 63) / 64;
    k_gemm<<<gB, 256, 0, stream>>>(x_in, nullptr, Wt[0], pre_b1, nullptr, nullptr, 1,
                                   nullptr, nullptr, nullptr, nullptr, hbf, NN);
    k_gemm<<<gB, 256, 0, stream>>>(nullptr, hbf, Wt[1], pre_b2, nullptr, nullptr, 0,
                                   nullptr, nullptr, nullptr, xf32, xbf, NN);
    for (int i = 0; i < 2; ++i) {
        k_gemm<<<gB, 256, 0, stream>>>(nullptr, xbf, Wt[2 + i], nullptr, nullptr, nullptr, 0,
                                       nullptr, nullptr, nullptr, nullptr, hbf, NN);
        k_agg<<<2048, 256, 0, stream>>>(hbf, rowstart, colx, wn, dis, conv_b + i * 128,
                                        xf32, zf32, bnsumb, bnsqb, NN);
        k_bnfin<<<1, 128, 0, stream>>>(bnsumb, bnsqb, bn_gamma + i * 128, bn_beta + i * 128,
                                       bnscale, bnshift, 1.0f / NN);
        k_gemm<<<gB, 256, 0, stream>>>(zf32, nullptr, Wt[4 + i], ffnn_b1 + i * 128, bnscale, bnshift, 1,
                                       nullptr, nullptr, nullptr, nullptr, hbf, NN);
        k_gemm<<<gB, 256, 0, stream>>>(nullptr, hbf, Wt[6 + i], ffnn_b2 + i * 128, nullptr, nullptr, 0,
                                       zf32, bnscale, bnshift, xf32, xbf, NN);
    }
    k_pool<<<GG, 128, 0, stream>>>(xf32, gstart, pooled, GG);
    k_post<<<GG, 128, 0, stream>>>(pooled, post_w1, post_b1, post_w2, post_b2, (float*)d_out, GG);
}